// Round 10
// baseline (507.476 us; speedup 1.0000x reference)
//
#include <hip/hip_runtime.h>
#include <stdint.h>

typedef unsigned short u16;
typedef unsigned int u32;
typedef unsigned long long u64;

typedef __attribute__((ext_vector_type(8))) __bf16 bf16x8;
typedef __attribute__((ext_vector_type(4))) float f32x4;

#define NROW 8192
#define DMODEL 256
#define HD 64
#define LDT 72   // LDS row stride (u16) for k_qkv/k_prep tiles

__device__ __forceinline__ u16 f2bf(float f) {   // RNE f32 -> bf16
    u32 u = __builtin_bit_cast(u32, f);
    u += 0x7FFFu + ((u >> 16) & 1u);
    return (u16)(u >> 16);
}
__device__ __forceinline__ bf16x8 ldb8(const u16* p) {
    uint4 v = *(const uint4*)p;
    return __builtin_bit_cast(bf16x8, v);
}
__device__ __forceinline__ f32x4 mfma16(bf16x8 a, bf16x8 b, f32x4 c) {
    return __builtin_amdgcn_mfma_f32_16x16x32_bf16(a, b, c, 0, 0, 0);
}

// ---------------- kernel P: x f32->bf16 ; W f32->bf16 transposed -----------
__global__ __launch_bounds__(256) void k_prep(
    const float* __restrict__ x,
    const float* __restrict__ Wq, const float* __restrict__ Wk,
    const float* __restrict__ Wv,
    u16* __restrict__ xb, u16* __restrict__ Wt) {
    const int t = threadIdx.x;
    if (blockIdx.x < 1024) {                       // x convert: 8 elems/thread
        size_t idx = (size_t)blockIdx.x * 2048 + t * 8;
        f32x4 a = *(const f32x4*)&x[idx];
        f32x4 b = *(const f32x4*)&x[idx + 4];
        uint4 o;
        o.x = (u32)f2bf(a[0]) | ((u32)f2bf(a[1]) << 16);
        o.y = (u32)f2bf(a[2]) | ((u32)f2bf(a[3]) << 16);
        o.z = (u32)f2bf(b[0]) | ((u32)f2bf(b[1]) << 16);
        o.w = (u32)f2bf(b[2]) | ((u32)f2bf(b[3]) << 16);
        *(uint4*)&xb[idx] = o;
        return;
    }
    // W transpose: 48 blocks, 64x64 tiles
    __shared__ __align__(16) u16 lw[64 * LDT];
    int wb = blockIdx.x - 1024;
    int mat = wb >> 4, tile = wb & 15;
    int k0 = (tile >> 2) * 64, n0 = (tile & 3) * 64;
    const float* W = (mat == 0) ? Wq : ((mat == 1) ? Wk : Wv);
    #pragma unroll
    for (int i = 0; i < 4; ++i) {
        int c = t + 256 * i;
        int k = c >> 4, c4 = c & 15;
        f32x4 w4 = *(const f32x4*)&W[(size_t)(k0 + k) * DMODEL + n0 + c4 * 4];
        uint2 pk;
        pk.x = (u32)f2bf(w4[0]) | ((u32)f2bf(w4[1]) << 16);
        pk.y = (u32)f2bf(w4[2]) | ((u32)f2bf(w4[3]) << 16);
        *(uint2*)&lw[k * LDT + c4 * 4] = pk;
    }
    __syncthreads();
    #pragma unroll
    for (int i = 0; i < 2; ++i) {
        int c = t + 256 * i;
        int n = c >> 3, k8 = c & 7;
        union { uint4 u; u16 s[8]; } pk;
        #pragma unroll
        for (int j = 0; j < 8; ++j) pk.s[j] = lw[(k8 * 8 + j) * LDT + n];
        *(uint4*)&Wt[(size_t)mat * 65536 + (size_t)(n0 + n) * DMODEL + k0 + k8 * 8] = pk.u;
    }
}

// ---------------- kernel 1: MERGED bitmask + QKV ---------------------------
// bid < 1024: edge -> bitmask (independent of prep). bid >= 1024: QKV proj.
__global__ __launch_bounds__(256, 3) void k_qkvmask(
    const int* __restrict__ edge, u64* __restrict__ bits,
    const u16* __restrict__ xb, const u16* __restrict__ Wt,
    const float* __restrict__ bq, const float* __restrict__ bk,
    const float* __restrict__ bv,
    u16* __restrict__ Qo, u16* __restrict__ Ko, u16* __restrict__ Vt) {
    __shared__ __align__(16) u16 ax[128 * LDT];
    __shared__ __align__(16) u16 wt[64 * LDT];
    __shared__ u64 lb[8][128];
    const int t = threadIdx.x;
    const int lane = t & 63, wv = t >> 6;

    if (blockIdx.x < 1024) {                       // ---- bitmask part ----
        const u32 m8 = blockIdx.x * 8u;
        #pragma unroll
        for (int rr = 0; rr < 2; ++rr) {
            const int mloc = wv * 2 + rr;
            const size_t base = (size_t)(m8 + mloc) * NROW;
            for (int nwb = 0; nwb < 128; nwb += 16) {
                int v[16];
                #pragma unroll
                for (int j = 0; j < 16; ++j)
                    v[j] = edge[base + (size_t)(nwb + j) * 64 + lane];
                u64 b[16];
                #pragma unroll
                for (int j = 0; j < 16; ++j) b[j] = __ballot(v[j] != 0);
                if (lane == 0) {
                    #pragma unroll
                    for (int j = 0; j < 16; ++j) lb[mloc][nwb + j] = b[j];
                }
            }
        }
        __syncthreads();
        const int nw = t >> 1, mh = (t & 1) * 4;
        u64 a0 = lb[mh + 0][nw], a1 = lb[mh + 1][nw];
        u64 a2 = lb[mh + 2][nw], a3 = lb[mh + 3][nw];
        u64* dst = &bits[(size_t)nw * NROW + m8 + mh];
        uint4 p0, p1;
        p0.x = (u32)a0; p0.y = (u32)(a0 >> 32); p0.z = (u32)a1; p0.w = (u32)(a1 >> 32);
        p1.x = (u32)a2; p1.y = (u32)(a2 >> 32); p1.z = (u32)a3; p1.w = (u32)(a3 >> 32);
        *(uint4*)dst = p0;
        *(uint4*)(dst + 2) = p1;
        return;
    }

    // ---- QKV part ----
    const int q = blockIdx.x - 1024;               // 0..767
    const int q4 = lane >> 4, l15 = lane & 15;
    const int wr = wv >> 1, wc = wv & 1;
    const int row0 = (q & 63) * 128;
    const int ymat = q >> 6;                       // 0..11
    const int mat = ymat >> 2;
    const int c0 = (ymat & 3) * 64;
    const u16* Wm = Wt + (size_t)mat * 65536;
    const float* bias = (mat == 0) ? bq : ((mat == 1) ? bk : bv);

    f32x4 acc[8];
    #pragma unroll
    for (int i = 0; i < 8; ++i) acc[i] = {0.f, 0.f, 0.f, 0.f};

    for (int kk = 0; kk < DMODEL; kk += 64) {
        #pragma unroll
        for (int i = 0; i < 4; ++i) {
            int c = t + 256 * i;
            int row = c >> 3, c8 = c & 7;
            *(uint4*)&ax[row * LDT + c8 * 8] =
                *(const uint4*)&xb[(size_t)(row0 + row) * DMODEL + kk + c8 * 8];
        }
        #pragma unroll
        for (int i = 0; i < 2; ++i) {
            int c = t + 256 * i;
            int n = c >> 3, c8 = c & 7;
            *(uint4*)&wt[n * LDT + c8 * 8] =
                *(const uint4*)&Wm[(size_t)(c0 + n) * DMODEL + kk + c8 * 8];
        }
        __syncthreads();
        #pragma unroll
        for (int ks = 0; ks < 2; ++ks) {
            bf16x8 xf[4], wf[2];
            #pragma unroll
            for (int it = 0; it < 4; ++it)
                xf[it] = ldb8(&ax[(wr * 64 + it * 16 + l15) * LDT + ks * 32 + q4 * 8]);
            #pragma unroll
            for (int jt = 0; jt < 2; ++jt)
                wf[jt] = ldb8(&wt[(wc * 32 + jt * 16 + l15) * LDT + ks * 32 + q4 * 8]);
            if (mat < 2) {
                #pragma unroll
                for (int it = 0; it < 4; ++it)
                    #pragma unroll
                    for (int jt = 0; jt < 2; ++jt)
                        acc[it * 2 + jt] = mfma16(xf[it], wf[jt], acc[it * 2 + jt]);
            } else {  // V: swapped operands -> D = (xW)^T
                #pragma unroll
                for (int jt = 0; jt < 2; ++jt)
                    #pragma unroll
                    for (int it = 0; it < 4; ++it)
                        acc[jt * 4 + it] = mfma16(wf[jt], xf[it], acc[jt * 4 + it]);
            }
        }
        __syncthreads();
    }

    if (mat < 2) {
        u16* out = (mat == 0) ? Qo : Ko;
        const float scale = (mat == 0) ? 0.18033688f : 1.0f;  // 0.125*log2(e)
        #pragma unroll
        for (int jt = 0; jt < 2; ++jt) {
            int col = c0 + wc * 32 + jt * 16 + l15;
            float bcol = bias[col];
            #pragma unroll
            for (int it = 0; it < 4; ++it) {
                int rowb = row0 + wr * 64 + it * 16 + q4 * 4;
                f32x4 a = acc[it * 2 + jt];
                #pragma unroll
                for (int r = 0; r < 4; ++r)
                    out[(size_t)(rowb + r) * DMODEL + col] = f2bf((a[r] + bcol) * scale);
            }
        }
    } else {
        #pragma unroll
        for (int jt = 0; jt < 2; ++jt) {
            #pragma unroll
            for (int r = 0; r < 4; ++r) {
                int drow = c0 + wc * 32 + jt * 16 + q4 * 4 + r;
                float bd = bias[drow];
                #pragma unroll
                for (int it = 0; it < 4; ++it) {
                    int col = row0 + wr * 64 + it * 16 + l15;
                    Vt[(size_t)drow * NROW + col] = f2bf(acc[jt * 4 + it][r] + bd);
                }
            }
        }
    }
}

// ---------------- kernel 2: flash attention, BM=256, split-K (4 slices) ----
// grid 512: sl=bid>>7; b7=bid&127: h=b7&3, qt=b7>>2 (0..31, 256 Q-rows each).
// 4 waves; each wave owns 64 Q-rows (four 16-row groups nt=0..3) -> kb/vb LDS
// reads amortized 4x (kb held in registers across nt). 32 K-tiles of 64 m.
// No-max exp2 softmax => partials additive. Writes unnormalized O^T
// [64 d][256 n] f32 + l[256]. XOR-swizzled LDS, double-buffered, 1 barrier/iter.
__global__ __launch_bounds__(256, 2) void k_attn(
    const u16* __restrict__ Q, const u16* __restrict__ K,
    const u16* __restrict__ Vt, const u64* __restrict__ bits,
    float* __restrict__ po) {
    __shared__ __align__(16) u16 sK[2][64 * 64];
    __shared__ __align__(16) u16 sV[2][64 * 64];
    __shared__ __align__(16) u16 sP[4][64 * 64];
    __shared__ __align__(16) u32 sB[2][4][2][64];  // [buf][ngroup][half][m]

    const int t = threadIdx.x;
    const int lane = t & 63, w = t >> 6;
    const int q4 = lane >> 4, l15 = lane & 15;
    const int l7 = l15 & 7;
    const int bid = blockIdx.x;
    const int sl = bid >> 7;
    const int b7 = bid & 127;
    const int h = b7 & 3;
    const int qt = b7 >> 2;
    const int n0 = qt * 256;
    const int mbase = sl * 2048;
    const int half = w >> 1;
    const u32 shift = (u32)((w & 1) * 16 + l15);
    const int sr = t >> 3, sc = t & 7;             // staging coords
    const int ssw = (sc ^ (sr & 7)) * 8;           // swizzled chunk offset
    const int bg = t >> 6, bm = t & 63;            // bits staging (all 256 thr)

    bf16x8 qf[4][2];
    #pragma unroll
    for (int nt = 0; nt < 4; ++nt)
        #pragma unroll
        for (int ks = 0; ks < 2; ++ks)
            qf[nt][ks] = ldb8(&Q[(size_t)(n0 + nt * 64 + w * 16 + l15) * DMODEL +
                                 h * HD + ks * 32 + q4 * 8]);

    uint4 onesu = {0x3F803F80u, 0x3F803F80u, 0x3F803F80u, 0x3F803F80u};
    const bf16x8 ones = __builtin_bit_cast(bf16x8, onesu);

    f32x4 o[4][4], lacc[4];
    #pragma unroll
    for (int nt = 0; nt < 4; ++nt) {
        lacc[nt] = {0.f, 0.f, 0.f, 0.f};
        #pragma unroll
        for (int dt = 0; dt < 4; ++dt) o[nt][dt] = {0.f, 0.f, 0.f, 0.f};
    }

    uint4 rk0, rk1, rv0, rv1; uint2 rb;
    {   // prefetch + commit tile 0 of this slice
        rk0 = *(const uint4*)&K[(size_t)(mbase + sr) * DMODEL + h * HD + sc * 8];
        rk1 = *(const uint4*)&K[(size_t)(mbase + 32 + sr) * DMODEL + h * HD + sc * 8];
        rv0 = *(const uint4*)&Vt[(size_t)(h * HD + sr) * NROW + mbase + sc * 8];
        rv1 = *(const uint4*)&Vt[(size_t)(h * HD + 32 + sr) * NROW + mbase + sc * 8];
        rb = *(const uint2*)&bits[(size_t)(qt * 4 + bg) * NROW + mbase + bm];
        *(uint4*)&sK[0][sr * 64 + ssw] = rk0;
        *(uint4*)&sK[0][(32 + sr) * 64 + ssw] = rk1;
        *(uint4*)&sV[0][sr * 64 + ssw] = rv0;
        *(uint4*)&sV[0][(32 + sr) * 64 + ssw] = rv1;
        sB[0][bg][0][bm] = rb.x; sB[0][bg][1][bm] = rb.y;
    }

    for (int it = 0; it < 32; ++it) {
        __syncthreads();
        const int buf = it & 1;
        if (it < 31) {                             // prefetch next tile
            int m0 = mbase + (it + 1) * 64;
            rk0 = *(const uint4*)&K[(size_t)(m0 + sr) * DMODEL + h * HD + sc * 8];
            rk1 = *(const uint4*)&K[(size_t)(m0 + 32 + sr) * DMODEL + h * HD + sc * 8];
            rv0 = *(const uint4*)&Vt[(size_t)(h * HD + sr) * NROW + m0 + sc * 8];
            rv1 = *(const uint4*)&Vt[(size_t)(h * HD + 32 + sr) * NROW + m0 + sc * 8];
            rb = *(const uint2*)&bits[(size_t)(qt * 4 + bg) * NROW + m0 + bm];
        }

        // load K fragments once; reuse across all 4 n-groups
        bf16x8 kb[2][4];
        #pragma unroll
        for (int ks = 0; ks < 2; ++ks)
            #pragma unroll
            for (int tj = 0; tj < 4; ++tj)
                kb[ks][tj] = ldb8(&sK[buf][(tj * 16 + l15) * 64 + (((ks * 4 + q4) ^ l7) * 8)]);

        #pragma unroll
        for (int nt = 0; nt < 4; ++nt) {           // S^T, mask, exp2, pack per group
            f32x4 s[4];
            #pragma unroll
            for (int tj = 0; tj < 4; ++tj) s[tj] = {0.f, 0.f, 0.f, 0.f};
            #pragma unroll
            for (int ks = 0; ks < 2; ++ks)
                #pragma unroll
                for (int tj = 0; tj < 4; ++tj)
                    s[tj] = mfma16(kb[ks][tj], qf[nt][ks], s[tj]);
            #pragma unroll
            for (int tj = 0; tj < 4; ++tj) {
                uint4 bw = *(const uint4*)&sB[buf][nt][half][tj * 16 + q4 * 4];
                u32 wd[4] = {bw.x, bw.y, bw.z, bw.w};
                u32 ub[4];
                #pragma unroll
                for (int r = 0; r < 4; ++r) {
                    float sv = ((wd[r] >> shift) & 1u) ? s[tj][r] : -1e30f;
                    ub[r] = __builtin_bit_cast(u32, __builtin_amdgcn_exp2f(sv));
                }
                uint2 pk;
                pk.x = (ub[0] >> 16) | (ub[1] & 0xFFFF0000u);
                pk.y = (ub[2] >> 16) | (ub[3] & 0xFFFF0000u);
                *(uint2*)&sP[w][(nt * 16 + l15) * 64 +
                                (((tj * 2 + (q4 >> 1)) ^ l7) * 8) + (q4 & 1) * 4] = pk;
            }
        }
        asm volatile("s_waitcnt lgkmcnt(0)" ::: "memory");  // sP is wave-private

        #pragma unroll
        for (int ks = 0; ks < 2; ++ks) {           // O += P V ; l += P 1
            bf16x8 vb[4];
            #pragma unroll
            for (int dt = 0; dt < 4; ++dt)
                vb[dt] = ldb8(&sV[buf][(dt * 16 + l15) * 64 + (((ks * 4 + q4) ^ l7) * 8)]);
            #pragma unroll
            for (int nt = 0; nt < 4; ++nt) {
                bf16x8 pf = ldb8(&sP[w][(nt * 16 + l15) * 64 + (((ks * 4 + q4) ^ l7) * 8)]);
                #pragma unroll
                for (int dt = 0; dt < 4; ++dt)
                    o[nt][dt] = mfma16(pf, vb[dt], o[nt][dt]);
                lacc[nt] = mfma16(pf, ones, lacc[nt]);
            }
        }

        if (it < 31) {                             // commit prefetched tile
            const int nb = buf ^ 1;
            *(uint4*)&sK[nb][sr * 64 + ssw] = rk0;
            *(uint4*)&sK[nb][(32 + sr) * 64 + ssw] = rk1;
            *(uint4*)&sV[nb][sr * 64 + ssw] = rv0;
            *(uint4*)&sV[nb][(32 + sr) * 64 + ssw] = rv1;
            sB[nb][bg][0][bm] = rb.x; sB[nb][bg][1][bm] = rb.y;
        }
    }

    // partial store: O^T as [64 d][256 n] f32 + l[256]
    float* pob = po + (size_t)bid * 16640;
    #pragma unroll
    for (int nt = 0; nt < 4; ++nt)
        #pragma unroll
        for (int dt = 0; dt < 4; ++dt)
            *(f32x4*)&pob[(dt * 16 + l15) * 256 + nt * 64 + w * 16 + q4 * 4] = o[nt][dt];
    if (l15 == 0) {
        #pragma unroll
        for (int nt = 0; nt < 4; ++nt)
            #pragma unroll
            for (int r = 0; r < 4; ++r)
                pob[16384 + nt * 64 + w * 16 + q4 * 4 + r] = lacc[nt][r];
    }
}

// ---------------- kernel 3: split-K reduce + normalize ---------------------
// grid 128: h=b&3, qt=b>>2. Sum 4 partials, divide by l, store f32 out.
__global__ __launch_bounds__(256) void k_reduce(const float* __restrict__ po,
                                                float* __restrict__ out) {
    __shared__ float sT[64 * 260];
    __shared__ float sL[256];
    const int t = threadIdx.x;
    const int b = blockIdx.x;
    const int h = b & 3;
    const int qt = b >> 2;
    const int n0 = qt * 256;
    const size_t base = (size_t)b * 16640;
    const int d = t >> 2, ng = (t & 3) * 64;
    f32x4 a[16];
    #pragma unroll
    for (int j = 0; j < 16; ++j) a[j] = {0.f, 0.f, 0.f, 0.f};
    #pragma unroll
    for (int s = 0; s < 4; ++s) {
        const float* p = po + base + (size_t)s * (128 * 16640) + d * 256 + ng;
        #pragma unroll
        for (int j = 0; j < 16; ++j) a[j] += *(const f32x4*)&p[j * 4];
    }
    #pragma unroll
    for (int j = 0; j < 16; ++j) *(f32x4*)&sT[d * 260 + ng + j * 4] = a[j];
    {
        float l = 0.f;
        #pragma unroll
        for (int s = 0; s < 4; ++s) l += po[base + (size_t)s * (128 * 16640) + 16384 + t];
        sL[t] = l;
    }
    __syncthreads();
    const int n = t;
    float inv = __builtin_amdgcn_rcpf(sL[n] + 1e-30f);
    #pragma unroll
    for (int j = 0; j < 16; ++j) {
        f32x4 v;
        #pragma unroll
        for (int i = 0; i < 4; ++i) v[i] = sT[(j * 4 + i) * 260 + n];
        v = v * inv;
        *(f32x4*)&out[(size_t)(n0 + n) * DMODEL + h * HD + j * 4] = v;
    }
}

extern "C" void kernel_launch(void* const* d_in, const int* in_sizes, int n_in,
                              void* d_out, int out_size, void* d_ws, size_t ws_size,
                              hipStream_t stream) {
    const float* x  = (const float*)d_in[0];
    const int* edge = (const int*)d_in[1];
    const float* Wq = (const float*)d_in[2];
    const float* bq = (const float*)d_in[3];
    const float* Wk = (const float*)d_in[4];
    const float* bk = (const float*)d_in[5];
    const float* Wv = (const float*)d_in[6];
    const float* bv = (const float*)d_in[7];

    char* ws = (char*)d_ws;
    u64* bits = (u64*)ws;                        //  8 MB
    u16* Qo  = (u16*)(ws + (8u << 20));          //  4 MB (bf16, Q pre-scaled)
    u16* Ko  = (u16*)(ws + (12u << 20));         //  4 MB (bf16)
    u16* Vt  = (u16*)(ws + (16u << 20));         //  4 MB (bf16, [256][8192])
    u16* xb  = (u16*)(ws + (20u << 20));         //  4 MB (bf16 x)
    u16* Wt  = (u16*)(ws + (24u << 20));         //  384 KB (bf16, 3x[256n][256k])
    float* po = (float*)(ws + (32u << 20));      //  34 MB (split-K partials)
    float* out = (float*)d_out;

    hipLaunchKernelGGL(k_prep, dim3(1072), dim3(256), 0, stream, x, Wq, Wk, Wv, xb, Wt);
    hipLaunchKernelGGL(k_qkvmask, dim3(1792), dim3(256), 0, stream,
                       edge, bits, xb, Wt, bq, bk, bv, Qo, Ko, Vt);
    hipLaunchKernelGGL(k_attn, dim3(512), dim3(256), 0, stream, Qo, Ko, Vt, bits, po);
    hipLaunchKernelGGL(k_reduce, dim3(128), dim3(256), 0, stream, po, out);
}

// Round 11
// 500.853 us; speedup vs baseline: 1.0132x; 1.0132x over previous
//
#include <hip/hip_runtime.h>
#include <stdint.h>

typedef unsigned short u16;
typedef unsigned int u32;
typedef unsigned long long u64;

typedef __attribute__((ext_vector_type(8))) __bf16 bf16x8;
typedef __attribute__((ext_vector_type(4))) float f32x4;

#define NROW 8192
#define DMODEL 256
#define HD 64
#define LDT 72   // LDS row stride (u16) for k_qkv/k_prep tiles

__device__ __forceinline__ u16 f2bf(float f) {   // RNE f32 -> bf16
    u32 u = __builtin_bit_cast(u32, f);
    u += 0x7FFFu + ((u >> 16) & 1u);
    return (u16)(u >> 16);
}
__device__ __forceinline__ bf16x8 ldb8(const u16* p) {
    uint4 v = *(const uint4*)p;
    return __builtin_bit_cast(bf16x8, v);
}
__device__ __forceinline__ f32x4 mfma16(bf16x8 a, bf16x8 b, f32x4 c) {
    return __builtin_amdgcn_mfma_f32_16x16x32_bf16(a, b, c, 0, 0, 0);
}

// ---------------- kernel P: x f32->bf16 ; W f32->bf16 transposed -----------
__global__ __launch_bounds__(256) void k_prep(
    const float* __restrict__ x,
    const float* __restrict__ Wq, const float* __restrict__ Wk,
    const float* __restrict__ Wv,
    u16* __restrict__ xb, u16* __restrict__ Wt) {
    const int t = threadIdx.x;
    if (blockIdx.x < 1024) {                       // x convert: 8 elems/thread
        size_t idx = (size_t)blockIdx.x * 2048 + t * 8;
        f32x4 a = *(const f32x4*)&x[idx];
        f32x4 b = *(const f32x4*)&x[idx + 4];
        uint4 o;
        o.x = (u32)f2bf(a[0]) | ((u32)f2bf(a[1]) << 16);
        o.y = (u32)f2bf(a[2]) | ((u32)f2bf(a[3]) << 16);
        o.z = (u32)f2bf(b[0]) | ((u32)f2bf(b[1]) << 16);
        o.w = (u32)f2bf(b[2]) | ((u32)f2bf(b[3]) << 16);
        *(uint4*)&xb[idx] = o;
        return;
    }
    // W transpose: 48 blocks, 64x64 tiles
    __shared__ __align__(16) u16 lw[64 * LDT];
    int wb = blockIdx.x - 1024;
    int mat = wb >> 4, tile = wb & 15;
    int k0 = (tile >> 2) * 64, n0 = (tile & 3) * 64;
    const float* W = (mat == 0) ? Wq : ((mat == 1) ? Wk : Wv);
    #pragma unroll
    for (int i = 0; i < 4; ++i) {
        int c = t + 256 * i;
        int k = c >> 4, c4 = c & 15;
        f32x4 w4 = *(const f32x4*)&W[(size_t)(k0 + k) * DMODEL + n0 + c4 * 4];
        uint2 pk;
        pk.x = (u32)f2bf(w4[0]) | ((u32)f2bf(w4[1]) << 16);
        pk.y = (u32)f2bf(w4[2]) | ((u32)f2bf(w4[3]) << 16);
        *(uint2*)&lw[k * LDT + c4 * 4] = pk;
    }
    __syncthreads();
    #pragma unroll
    for (int i = 0; i < 2; ++i) {
        int c = t + 256 * i;
        int n = c >> 3, k8 = c & 7;
        union { uint4 u; u16 s[8]; } pk;
        #pragma unroll
        for (int j = 0; j < 8; ++j) pk.s[j] = lw[(k8 * 8 + j) * LDT + n];
        *(uint4*)&Wt[(size_t)mat * 65536 + (size_t)(n0 + n) * DMODEL + k0 + k8 * 8] = pk.u;
    }
}

// ---------------- kernel 1: MERGED bitmask + QKV ---------------------------
// bid < 1024: edge -> bitmask. bid >= 1024: QKV proj. (independent halves
// overlap on the GPU instead of serializing as two launches)
__global__ __launch_bounds__(256, 3) void k_qkvmask(
    const int* __restrict__ edge, u64* __restrict__ bits,
    const u16* __restrict__ xb, const u16* __restrict__ Wt,
    const float* __restrict__ bq, const float* __restrict__ bk,
    const float* __restrict__ bv,
    u16* __restrict__ Qo, u16* __restrict__ Ko, u16* __restrict__ Vt) {
    __shared__ __align__(16) u16 ax[128 * LDT];
    __shared__ __align__(16) u16 wt[64 * LDT];
    __shared__ u64 lb[8][128];
    const int t = threadIdx.x;
    const int lane = t & 63, wv = t >> 6;

    if (blockIdx.x < 1024) {                       // ---- bitmask part ----
        const u32 m8 = blockIdx.x * 8u;
        #pragma unroll
        for (int rr = 0; rr < 2; ++rr) {
            const int mloc = wv * 2 + rr;
            const size_t base = (size_t)(m8 + mloc) * NROW;
            for (int nwb = 0; nwb < 128; nwb += 16) {
                int v[16];
                #pragma unroll
                for (int j = 0; j < 16; ++j)
                    v[j] = edge[base + (size_t)(nwb + j) * 64 + lane];
                u64 b[16];
                #pragma unroll
                for (int j = 0; j < 16; ++j) b[j] = __ballot(v[j] != 0);
                if (lane == 0) {
                    #pragma unroll
                    for (int j = 0; j < 16; ++j) lb[mloc][nwb + j] = b[j];
                }
            }
        }
        __syncthreads();
        const int nw = t >> 1, mh = (t & 1) * 4;
        u64 a0 = lb[mh + 0][nw], a1 = lb[mh + 1][nw];
        u64 a2 = lb[mh + 2][nw], a3 = lb[mh + 3][nw];
        u64* dst = &bits[(size_t)nw * NROW + m8 + mh];
        uint4 p0, p1;
        p0.x = (u32)a0; p0.y = (u32)(a0 >> 32); p0.z = (u32)a1; p0.w = (u32)(a1 >> 32);
        p1.x = (u32)a2; p1.y = (u32)(a2 >> 32); p1.z = (u32)a3; p1.w = (u32)(a3 >> 32);
        *(uint4*)dst = p0;
        *(uint4*)(dst + 2) = p1;
        return;
    }

    // ---- QKV part ----
    const int q = blockIdx.x - 1024;               // 0..767
    const int q4 = lane >> 4, l15 = lane & 15;
    const int wr = wv >> 1, wc = wv & 1;
    const int row0 = (q & 63) * 128;
    const int ymat = q >> 6;                       // 0..11
    const int mat = ymat >> 2;
    const int c0 = (ymat & 3) * 64;
    const u16* Wm = Wt + (size_t)mat * 65536;
    const float* bias = (mat == 0) ? bq : ((mat == 1) ? bk : bv);

    f32x4 acc[8];
    #pragma unroll
    for (int i = 0; i < 8; ++i) acc[i] = {0.f, 0.f, 0.f, 0.f};

    for (int kk = 0; kk < DMODEL; kk += 64) {
        #pragma unroll
        for (int i = 0; i < 4; ++i) {
            int c = t + 256 * i;
            int row = c >> 3, c8 = c & 7;
            *(uint4*)&ax[row * LDT + c8 * 8] =
                *(const uint4*)&xb[(size_t)(row0 + row) * DMODEL + kk + c8 * 8];
        }
        #pragma unroll
        for (int i = 0; i < 2; ++i) {
            int c = t + 256 * i;
            int n = c >> 3, c8 = c & 7;
            *(uint4*)&wt[n * LDT + c8 * 8] =
                *(const uint4*)&Wm[(size_t)(c0 + n) * DMODEL + kk + c8 * 8];
        }
        __syncthreads();
        #pragma unroll
        for (int ks = 0; ks < 2; ++ks) {
            bf16x8 xf[4], wf[2];
            #pragma unroll
            for (int it = 0; it < 4; ++it)
                xf[it] = ldb8(&ax[(wr * 64 + it * 16 + l15) * LDT + ks * 32 + q4 * 8]);
            #pragma unroll
            for (int jt = 0; jt < 2; ++jt)
                wf[jt] = ldb8(&wt[(wc * 32 + jt * 16 + l15) * LDT + ks * 32 + q4 * 8]);
            if (mat < 2) {
                #pragma unroll
                for (int it = 0; it < 4; ++it)
                    #pragma unroll
                    for (int jt = 0; jt < 2; ++jt)
                        acc[it * 2 + jt] = mfma16(xf[it], wf[jt], acc[it * 2 + jt]);
            } else {  // V: swapped operands -> D = (xW)^T
                #pragma unroll
                for (int jt = 0; jt < 2; ++jt)
                    #pragma unroll
                    for (int it = 0; it < 4; ++it)
                        acc[jt * 4 + it] = mfma16(wf[jt], xf[it], acc[jt * 4 + it]);
            }
        }
        __syncthreads();
    }

    if (mat < 2) {
        u16* out = (mat == 0) ? Qo : Ko;
        const float scale = (mat == 0) ? 0.18033688f : 1.0f;  // 0.125*log2(e)
        #pragma unroll
        for (int jt = 0; jt < 2; ++jt) {
            int col = c0 + wc * 32 + jt * 16 + l15;
            float bcol = bias[col];
            #pragma unroll
            for (int it = 0; it < 4; ++it) {
                int rowb = row0 + wr * 64 + it * 16 + q4 * 4;
                f32x4 a = acc[it * 2 + jt];
                #pragma unroll
                for (int r = 0; r < 4; ++r)
                    out[(size_t)(rowb + r) * DMODEL + col] = f2bf((a[r] + bcol) * scale);
            }
        }
    } else {
        #pragma unroll
        for (int jt = 0; jt < 2; ++jt) {
            #pragma unroll
            for (int r = 0; r < 4; ++r) {
                int drow = c0 + wc * 32 + jt * 16 + q4 * 4 + r;
                float bd = bias[drow];
                #pragma unroll
                for (int it = 0; it < 4; ++it) {
                    int col = row0 + wr * 64 + it * 16 + l15;
                    Vt[(size_t)drow * NROW + col] = f2bf(acc[jt * 4 + it][r] + bd);
                }
            }
        }
    }
}

// ---------------- kernel 2: flash attention, BM=128, split-K (4 slices) ----
// (R9's measured-best config.) grid 1024: sl=bid>>8; b8=bid&255: h=b8&3,
// qt=b8>>2 (128 Q-rows each). 4 waves; each wave owns 32 Q-rows (two 16-row
// groups) -> kb/vb LDS reads amortized 2x. 32 K-tiles of 64 m per block.
// No-max exp2 softmax => partials additive. Writes unnormalized O^T
// [64 d][128 n] f32 + l[128]. XOR-swizzled LDS, double-buffered, 1 barrier/iter.
__global__ __launch_bounds__(256, 3) void k_attn(
    const u16* __restrict__ Q, const u16* __restrict__ K,
    const u16* __restrict__ Vt, const u64* __restrict__ bits,
    float* __restrict__ po) {
    __shared__ __align__(16) u16 sK[2][64 * 64];
    __shared__ __align__(16) u16 sV[2][64 * 64];
    __shared__ __align__(16) u16 sP[4][32 * 64];
    __shared__ __align__(16) u32 sB[2][2][2][64];  // [buf][ngroup][half][m]

    const int t = threadIdx.x;
    const int lane = t & 63, w = t >> 6;
    const int q4 = lane >> 4, l15 = lane & 15;
    const int l7 = l15 & 7;
    const int bid = blockIdx.x;
    const int sl = bid >> 8;
    const int b8 = bid & 255;
    const int h = b8 & 3;
    const int qt = b8 >> 2;
    const int n0 = qt * 128;
    const int mbase = sl * 2048;
    const int half = w >> 1;
    const u32 shift = (u32)((w & 1) * 16 + l15);
    const int sr = t >> 3, sc = t & 7;             // staging coords
    const int ssw = (sc ^ (sr & 7)) * 8;           // swizzled chunk offset
    const int bg = t >> 6, bm = t & 63;            // bits staging (t<128)

    bf16x8 qf[2][2];
    #pragma unroll
    for (int nt = 0; nt < 2; ++nt)
        #pragma unroll
        for (int ks = 0; ks < 2; ++ks)
            qf[nt][ks] = ldb8(&Q[(size_t)(n0 + nt * 64 + w * 16 + l15) * DMODEL +
                                 h * HD + ks * 32 + q4 * 8]);

    uint4 onesu = {0x3F803F80u, 0x3F803F80u, 0x3F803F80u, 0x3F803F80u};
    const bf16x8 ones = __builtin_bit_cast(bf16x8, onesu);

    f32x4 o[2][4], lacc[2];
    #pragma unroll
    for (int nt = 0; nt < 2; ++nt) {
        lacc[nt] = {0.f, 0.f, 0.f, 0.f};
        #pragma unroll
        for (int dt = 0; dt < 4; ++dt) o[nt][dt] = {0.f, 0.f, 0.f, 0.f};
    }

    uint4 rk0, rk1, rv0, rv1; uint2 rb;
    {   // prefetch + commit tile 0 of this slice
        rk0 = *(const uint4*)&K[(size_t)(mbase + sr) * DMODEL + h * HD + sc * 8];
        rk1 = *(const uint4*)&K[(size_t)(mbase + 32 + sr) * DMODEL + h * HD + sc * 8];
        rv0 = *(const uint4*)&Vt[(size_t)(h * HD + sr) * NROW + mbase + sc * 8];
        rv1 = *(const uint4*)&Vt[(size_t)(h * HD + 32 + sr) * NROW + mbase + sc * 8];
        if (t < 128) rb = *(const uint2*)&bits[(size_t)(qt * 2 + bg) * NROW + mbase + bm];
        *(uint4*)&sK[0][sr * 64 + ssw] = rk0;
        *(uint4*)&sK[0][(32 + sr) * 64 + ssw] = rk1;
        *(uint4*)&sV[0][sr * 64 + ssw] = rv0;
        *(uint4*)&sV[0][(32 + sr) * 64 + ssw] = rv1;
        if (t < 128) { sB[0][bg][0][bm] = rb.x; sB[0][bg][1][bm] = rb.y; }
    }

    for (int it = 0; it < 32; ++it) {
        __syncthreads();
        const int buf = it & 1;
        if (it < 31) {                             // prefetch next tile
            int m0 = mbase + (it + 1) * 64;
            rk0 = *(const uint4*)&K[(size_t)(m0 + sr) * DMODEL + h * HD + sc * 8];
            rk1 = *(const uint4*)&K[(size_t)(m0 + 32 + sr) * DMODEL + h * HD + sc * 8];
            rv0 = *(const uint4*)&Vt[(size_t)(h * HD + sr) * NROW + m0 + sc * 8];
            rv1 = *(const uint4*)&Vt[(size_t)(h * HD + 32 + sr) * NROW + m0 + sc * 8];
            if (t < 128) rb = *(const uint2*)&bits[(size_t)(qt * 2 + bg) * NROW + m0 + bm];
        }

        f32x4 s[2][4];
        #pragma unroll
        for (int nt = 0; nt < 2; ++nt)
            #pragma unroll
            for (int tj = 0; tj < 4; ++tj) s[nt][tj] = {0.f, 0.f, 0.f, 0.f};
        #pragma unroll
        for (int ks = 0; ks < 2; ++ks) {           // S^T = K Q^T (log2 domain)
            bf16x8 kb[4];
            #pragma unroll
            for (int tj = 0; tj < 4; ++tj)
                kb[tj] = ldb8(&sK[buf][(tj * 16 + l15) * 64 + (((ks * 4 + q4) ^ l7) * 8)]);
            #pragma unroll
            for (int nt = 0; nt < 2; ++nt)
                #pragma unroll
                for (int tj = 0; tj < 4; ++tj)
                    s[nt][tj] = mfma16(kb[tj], qf[nt][ks], s[nt][tj]);
        }

        #pragma unroll
        for (int nt = 0; nt < 2; ++nt) {           // mask + exp2 + pack b64 -> LDS
            #pragma unroll
            for (int tj = 0; tj < 4; ++tj) {
                uint4 bw = *(const uint4*)&sB[buf][nt][half][tj * 16 + q4 * 4];
                u32 wd[4] = {bw.x, bw.y, bw.z, bw.w};
                u32 ub[4];
                #pragma unroll
                for (int r = 0; r < 4; ++r) {
                    float sv = ((wd[r] >> shift) & 1u) ? s[nt][tj][r] : -1e30f;
                    ub[r] = __builtin_bit_cast(u32, __builtin_amdgcn_exp2f(sv));
                }
                uint2 pk;
                pk.x = (ub[0] >> 16) | (ub[1] & 0xFFFF0000u);
                pk.y = (ub[2] >> 16) | (ub[3] & 0xFFFF0000u);
                *(uint2*)&sP[w][(nt * 16 + l15) * 64 +
                                (((tj * 2 + (q4 >> 1)) ^ l7) * 8) + (q4 & 1) * 4] = pk;
            }
        }
        asm volatile("s_waitcnt lgkmcnt(0)" ::: "memory");  // sP is wave-private

        #pragma unroll
        for (int ks = 0; ks < 2; ++ks) {           // O += P V ; l += P 1
            bf16x8 pf[2], vb[4];
            #pragma unroll
            for (int nt = 0; nt < 2; ++nt)
                pf[nt] = ldb8(&sP[w][(nt * 16 + l15) * 64 + (((ks * 4 + q4) ^ l7) * 8)]);
            #pragma unroll
            for (int dt = 0; dt < 4; ++dt)
                vb[dt] = ldb8(&sV[buf][(dt * 16 + l15) * 64 + (((ks * 4 + q4) ^ l7) * 8)]);
            #pragma unroll
            for (int nt = 0; nt < 2; ++nt) {
                #pragma unroll
                for (int dt = 0; dt < 4; ++dt)
                    o[nt][dt] = mfma16(pf[nt], vb[dt], o[nt][dt]);
                lacc[nt] = mfma16(pf[nt], ones, lacc[nt]);
            }
        }

        if (it < 31) {                             // commit prefetched tile
            const int nb = buf ^ 1;
            *(uint4*)&sK[nb][sr * 64 + ssw] = rk0;
            *(uint4*)&sK[nb][(32 + sr) * 64 + ssw] = rk1;
            *(uint4*)&sV[nb][sr * 64 + ssw] = rv0;
            *(uint4*)&sV[nb][(32 + sr) * 64 + ssw] = rv1;
            if (t < 128) { sB[nb][bg][0][bm] = rb.x; sB[nb][bg][1][bm] = rb.y; }
        }
    }

    // partial store: O^T as [64 d][128 n] f32 + l[128]
    float* pob = po + (size_t)bid * 8320;
    #pragma unroll
    for (int nt = 0; nt < 2; ++nt)
        #pragma unroll
        for (int dt = 0; dt < 4; ++dt)
            *(f32x4*)&pob[(dt * 16 + l15) * 128 + nt * 64 + w * 16 + q4 * 4] = o[nt][dt];
    if (l15 == 0) {
        #pragma unroll
        for (int nt = 0; nt < 2; ++nt)
            #pragma unroll
            for (int r = 0; r < 4; ++r)
                pob[8192 + nt * 64 + w * 16 + q4 * 4 + r] = lacc[nt][r];
    }
}

// ---------------- kernel 3: split-K reduce + normalize ---------------------
// grid 256: h=b8&3, qt=b8>>2. Sum 4 partials, divide by l, store f32 out.
__global__ __launch_bounds__(256) void k_reduce(const float* __restrict__ po,
                                                float* __restrict__ out) {
    __shared__ float sT[64 * 132];
    __shared__ float sL[128];
    const int t = threadIdx.x;
    const int b8 = blockIdx.x;
    const int h = b8 & 3;
    const int qt = b8 >> 2;
    const int n0 = qt * 128;
    const size_t base = (size_t)b8 * 8320;
    const int d = t >> 2, ng = (t & 3) * 32;
    f32x4 a[8];
    #pragma unroll
    for (int j = 0; j < 8; ++j) a[j] = {0.f, 0.f, 0.f, 0.f};
    #pragma unroll
    for (int s = 0; s < 4; ++s) {
        const float* p = po + base + (size_t)s * (256 * 8320) + d * 128 + ng;
        #pragma unroll
        for (int j = 0; j < 8; ++j) a[j] += *(const f32x4*)&p[j * 4];
    }
    #pragma unroll
    for (int j = 0; j < 8; ++j) *(f32x4*)&sT[d * 132 + ng + j * 4] = a[j];
    if (t < 128) {
        float l = 0.f;
        #pragma unroll
        for (int s = 0; s < 4; ++s) l += po[base + (size_t)s * (256 * 8320) + 8192 + t];
        sL[t] = l;
    }
    __syncthreads();
    const int n = t >> 1, dg = (t & 1) * 32;
    float inv = __builtin_amdgcn_rcpf(sL[n] + 1e-30f);
    #pragma unroll
    for (int j = 0; j < 8; ++j) {
        f32x4 v;
        #pragma unroll
        for (int i = 0; i < 4; ++i) v[i] = sT[(dg + j * 4 + i) * 132 + n];
        v = v * inv;
        *(f32x4*)&out[(size_t)(n0 + n) * DMODEL + h * HD + dg + j * 4] = v;
    }
}

extern "C" void kernel_launch(void* const* d_in, const int* in_sizes, int n_in,
                              void* d_out, int out_size, void* d_ws, size_t ws_size,
                              hipStream_t stream) {
    const float* x  = (const float*)d_in[0];
    const int* edge = (const int*)d_in[1];
    const float* Wq = (const float*)d_in[2];
    const float* bq = (const float*)d_in[3];
    const float* Wk = (const float*)d_in[4];
    const float* bk = (const float*)d_in[5];
    const float* Wv = (const float*)d_in[6];
    const float* bv = (const float*)d_in[7];

    char* ws = (char*)d_ws;
    u64* bits = (u64*)ws;                        //  8 MB
    u16* Qo  = (u16*)(ws + (8u << 20));          //  4 MB (bf16, Q pre-scaled)
    u16* Ko  = (u16*)(ws + (12u << 20));         //  4 MB (bf16)
    u16* Vt  = (u16*)(ws + (16u << 20));         //  4 MB (bf16, [256][8192])
    u16* xb  = (u16*)(ws + (20u << 20));         //  4 MB (bf16 x)
    u16* Wt  = (u16*)(ws + (24u << 20));         //  384 KB (bf16, 3x[256n][256k])
    float* po = (float*)(ws + (32u << 20));      //  34 MB (split-K partials)
    float* out = (float*)d_out;

    hipLaunchKernelGGL(k_prep, dim3(1072), dim3(256), 0, stream, x, Wq, Wk, Wv, xb, Wt);
    hipLaunchKernelGGL(k_qkvmask, dim3(1792), dim3(256), 0, stream,
                       edge, bits, xb, Wt, bq, bk, bv, Qo, Ko, Vt);
    hipLaunchKernelGGL(k_attn, dim3(1024), dim3(256), 0, stream, Qo, Ko, Vt, bits, po);
    hipLaunchKernelGGL(k_reduce, dim3(256), dim3(256), 0, stream, po, out);
}